// Round 6
// baseline (103.955 us; speedup 1.0000x reference)
//
#include <hip/hip_runtime.h>
#include <hip/hip_bf16.h>
#include <stdint.h>

#define NPTS 4096
#define NNBR 16      // neighbors kept (reference keeps 17 incl. self, drops self)
#define PPB  16      // points per block
#define NSEG 32      // candidate segments (one per t>>4 group)
#define SEGLEN 128   // candidates per segment
#define SEGPAD 132   // 132 % 32 == 4: the 4 segs in a wave land on bank-quads 0/4/8/12
#define HSTR 129     // heads stride in floats (odd-ish to break 16-pt bank alignment)
#define LSTR 65      // list/plist stride (65 % 32 == 1)
#define CAP  64      // accepted-candidate capacity (rank(tau) ~ 30-40)
#define BIGD 3.4e38f

// ---------------------------------------------------------------------------
// Distance with operation order pinned to the numpy reference (no FMA):
//   sq = (x*x + y*y) + z*z ; dot = (px*cx + py*cy) + pz*cz ; d2 = (sqp+sqq) - (dot+dot)
// sqq is precomputed once at staging (sw array) with the same pinned sqnorm, so
// every d2 evaluation in every phase is bitwise identical. Self d2 == +0.0.
// ---------------------------------------------------------------------------
__device__ __forceinline__ float sqnorm(float x, float y, float z) {
    return __fadd_rn(__fadd_rn(__fmul_rn(x, x), __fmul_rn(y, y)), __fmul_rn(z, z));
}
__device__ __forceinline__ float d2w(float px, float py, float pz, float sqp,
                                     float cx, float cy, float cz, float sqq) {
    const float dot = __fadd_rn(__fadd_rn(__fmul_rn(px, cx), __fmul_rn(py, cy)),
                                __fmul_rn(pz, cz));
    return __fsub_rn(__fadd_rn(sqp, sqq), __fadd_rn(dot, dot));
}

// depth-4 distance-only min/max ladder on named regs (2 VALU/slot, no VCC)
#define LAD4(S) { float lo_;                                      \
    lo_ = fminf(S, a0); S = fmaxf(S, a0); a0 = lo_;               \
    lo_ = fminf(S, a1); S = fmaxf(S, a1); a1 = lo_;               \
    lo_ = fminf(S, a2); S = fmaxf(S, a2); a2 = lo_;               \
    lo_ = fminf(S, a3); S = fmaxf(S, a3); a3 = lo_; }

// generic K-deep ladder over a register array (static unroll only)
#define LADK(AD, K, S)                                            \
    _Pragma("unroll")                                             \
    for (int k_ = 0; k_ < (K); ++k_) {                            \
        const float lo_ = fminf((S), AD[k_]);                     \
        (S) = fmaxf((S), AD[k_]);                                 \
        AD[k_] = lo_;                                             \
    }

// ---------------------------------------------------------------------------
// Fused exact 16-NN. Block = 512 thr = 16 points x 32 segments, grid = 1024.
//  scan1 : per-seg top-4 d2 (distance-only ladder), self included (d2==+0.0).
//  tau   : heads[pt][128] in LDS; 2 threads/pt LAD17 one 64-value half each
//          (rotated reads); tau = min(17th(H1), 17th(H2)) >= true d2_(17).
//  scan2 : branchless {d2 <= tau} bitmask per 32-cand word; sparse extraction
//          appends candidate INDEX to per-point LDS list (atomic, CAP=64).
//  final : round-5-proven 3-phase select, d2 recomputed (bitwise-identical)
//          from the staged SoA arrays; marking pass emits the 16 indices.
// Lane mapping pt = t&15, seg = t>>4: a wave holds 4 segments x 16 points ->
// 16-lane broadcast per address, 4 rows on distinct bank-quads (SEGPAD=132).
// ---------------------------------------------------------------------------
__global__ __launch_bounds__(512, 4) void knn_kernel(const float* __restrict__ x0,
                                                     ushort* __restrict__ nbr) {
    __shared__ float sx[NSEG * SEGPAD], sy[NSEG * SEGPAD],
                     sz[NSEG * SEGPAD], sw[NSEG * SEGPAD];   // 4 x 16,896 B
    __shared__ __align__(16) float mbuf[PPB * HSTR];         // heads; later plist
    __shared__ uint  list[PPB * LSTR];                       // accepted indices
    __shared__ float ttau[PPB][2];
    __shared__ float t16[PPB];
    __shared__ int   cnt[PPB], cnt2[PPB];

    const int b     = blockIdx.x >> 8;       // 256 chunks per batch
    const int chunk = blockIdx.x & 255;
    const float* Xb = x0 + b * (NPTS * 3);
    const int t = threadIdx.x;

    for (int i = t; i < NPTS; i += 512) {
        const int a = (i >> 7) * SEGPAD + (i & 127);
        const float x = Xb[3 * i + 0];
        const float y = Xb[3 * i + 1];
        const float z = Xb[3 * i + 2];
        sx[a] = x; sy[a] = y; sz[a] = z; sw[a] = sqnorm(x, y, z);
    }
    if (t < PPB) { cnt[t] = 0; cnt2[t] = 0; }
    __syncthreads();

    const int pt = t & 15, seg = t >> 4;     // seg 0..31
    const int p  = chunk * PPB + pt;         // batch-local point id
    const int pa = (p >> 7) * SEGPAD + (p & 127);
    const float px = sx[pa], py = sy[pa], pz = sz[pa], sqp = sw[pa];
    const int sb = seg * SEGPAD;

    // ---- scan1: per-seg top-4 (ascending a0..a3; self d2 == +0.0) ----
    float a0 = BIGD, a1 = BIGD, a2 = BIGD, a3 = BIGD;
    for (int j = 0; j < 32; ++j) {
        const int o = sb + 4 * j;
        const float4 cx4 = *(const float4*)&sx[o];
        const float4 cy4 = *(const float4*)&sy[o];
        const float4 cz4 = *(const float4*)&sz[o];
        const float4 cw4 = *(const float4*)&sw[o];
        float s0 = d2w(px, py, pz, sqp, cx4.x, cy4.x, cz4.x, cw4.x);
        float s1 = d2w(px, py, pz, sqp, cx4.y, cy4.y, cz4.y, cw4.y);
        float s2 = d2w(px, py, pz, sqp, cx4.z, cy4.z, cz4.z, cw4.z);
        float s3 = d2w(px, py, pz, sqp, cx4.w, cy4.w, cz4.w, cw4.w);
        LAD4(s0) LAD4(s1) LAD4(s2) LAD4(s3)
    }
    {
        float* hd = mbuf + pt * HSTR + seg * 4;
        hd[0] = a0; hd[1] = a1; hd[2] = a2; hd[3] = a3;
    }
    __syncthreads();

    // ---- tau: 2 threads/pt, LAD17 over one 64-value half (rotated reads) ----
    if (t < 32) {
        const int pm = t >> 1, half = t & 1;
        float ad[17];
#pragma unroll
        for (int k = 0; k < 17; ++k) ad[k] = BIGD;
        const int base = pm * HSTR + half * 64;
        for (int e = 0; e < 64; ++e) {
            float s = mbuf[base + ((e + t) & 63)];
            LADK(ad, 17, s)
        }
        ttau[pm][half] = ad[16];             // this half's 17th-smallest
    }
    __syncthreads();

    // ---- scan2: branchless accept-bitmask per 32-cand word + extraction ----
    const float tv = fminf(ttau[pt][0], ttau[pt][1]);
    for (int w = 0; w < 4; ++w) {
        uint m = 0;
#pragma unroll
        for (int jj = 0; jj < 8; ++jj) {
            const int o = sb + w * 32 + 4 * jj;
            const float4 cx4 = *(const float4*)&sx[o];
            const float4 cy4 = *(const float4*)&sy[o];
            const float4 cz4 = *(const float4*)&sz[o];
            const float4 cw4 = *(const float4*)&sw[o];
            const float s0 = d2w(px, py, pz, sqp, cx4.x, cy4.x, cz4.x, cw4.x);
            const float s1 = d2w(px, py, pz, sqp, cx4.y, cy4.y, cz4.y, cw4.y);
            const float s2 = d2w(px, py, pz, sqp, cx4.z, cy4.z, cz4.z, cw4.z);
            const float s3 = d2w(px, py, pz, sqp, cx4.w, cy4.w, cz4.w, cw4.w);
            m |= (s0 <= tv) ? (1u << (4 * jj + 0)) : 0u;
            m |= (s1 <= tv) ? (1u << (4 * jj + 1)) : 0u;
            m |= (s2 <= tv) ? (1u << (4 * jj + 2)) : 0u;
            m |= (s3 <= tv) ? (1u << (4 * jj + 3)) : 0u;
        }
        while (m) {                          // ~0.8 set bits/thread total
            const int bpos = __ffs(m) - 1;
            m &= m - 1;
            const int q = seg * SEGLEN + w * 32 + bpos;   // batch-local cand id
            if (q != p) {
                const int o = atomicAdd(&cnt[pt], 1);
                if (o < CAP) list[pt * LSTR + o] = (uint)q;
            }
        }
    }
    __syncthreads();

    // ---- final 3a: 4 threads/pt, LAD16 over stride-4 slice (d2 recomputed) ----
    if (t < 64) {
        const int p2 = t >> 2, sl = t & 3;
        const int n  = min(cnt[p2], CAP);
        const int pg  = chunk * PPB + p2;
        const int pa2 = (pg >> 7) * SEGPAD + (pg & 127);
        const float ax = sx[pa2], ay = sy[pa2], az = sz[pa2], sqa = sw[pa2];
        float ad[16];
#pragma unroll
        for (int k = 0; k < 16; ++k) ad[k] = BIGD;
        for (int e = sl; e < n; e += 4) {
            const int q  = (int)list[p2 * LSTR + e];
            const int qa = (q >> 7) * SEGPAD + (q & 127);
            float s = d2w(ax, ay, az, sqa, sx[qa], sy[qa], sz[qa], sw[qa]);
            LADK(ad, 16, s)
        }
#pragma unroll
        for (int k = 0; k < 16; ++k) mbuf[p2 * LSTR + sl * 16 + k] = ad[k];
    }
    __syncthreads();

    // ---- final 3b: 1 thread/pt, exact 16th-smallest among accepted ----
    if (t < PPB) {
        float ad[16];
#pragma unroll
        for (int k = 0; k < 16; ++k) ad[k] = BIGD;
        for (int e = 0; e < 64; ++e) {
            float s = mbuf[t * LSTR + ((e + 4 * t) & 63)];
            LADK(ad, 16, s)
        }
        t16[t] = ad[15];
    }
    __syncthreads();

    // ---- final 3c: marking pass emits the 16 indices with d2 <= th ----
    if (t < 64) {
        const int p2 = t >> 2, sl = t & 3;
        const int n  = min(cnt[p2], CAP);
        const int pg  = chunk * PPB + p2;
        const int pa2 = (pg >> 7) * SEGPAD + (pg & 127);
        const float ax = sx[pa2], ay = sy[pa2], az = sz[pa2], sqa = sw[pa2];
        const float th = t16[p2];
        const uint base = (uint)(b * NPTS + pg) * (uint)NNBR;
        for (int e = sl; e < n; e += 4) {
            const int q  = (int)list[p2 * LSTR + e];
            const int qa = (q >> 7) * SEGPAD + (q & 127);
            const float s = d2w(ax, ay, az, sqa, sx[qa], sy[qa], sz[qa], sw[qa]);
            if (s <= th) {
                const int o = atomicAdd(&cnt2[p2], 1);
                if (o < NNBR) nbr[base + o] = (ushort)q;
            }
        }
    }
}

// ---------------------------------------------------------------------------
// MLP + neighbor mean (one wave per point, lane = output channel) with the
// v0 passthrough copy folded in (first 48 blocks copy one float4/thread).
// ---------------------------------------------------------------------------
__global__ __launch_bounds__(256) void mlp_kernel(const float* __restrict__ x0,
                                                  const float* __restrict__ v0,
                                                  const float* __restrict__ W,
                                                  const float* __restrict__ bias,
                                                  const ushort* __restrict__ nbr,
                                                  float* __restrict__ out) {
    const int t   = threadIdx.x;
    const int gid = blockIdx.x * 256 + t;
    if (gid < (4 * NPTS * 3) / 4) {                 // 12288 float4 copies
        ((float4*)(out + 4 * NPTS * 64))[gid] = ((const float4*)v0)[gid];
    }

    const int wave = t >> 6;
    const int lane = t & 63;
    const int gp   = blockIdx.x * 4 + wave;         // global point id 0..16383
    const int b    = gp >> 12;
    const int p    = gp & (NPTS - 1);

    const float* Xb = x0 + b * (NPTS * 3);
    const float* Vb = v0 + b * (NPTS * 3);

    float w[12];
#pragma unroll
    for (int k = 0; k < 12; ++k) w[k] = W[k * 64 + lane];
    const float bb = bias[lane];

    const float xi0 = Xb[p * 3 + 0], xi1 = Xb[p * 3 + 1], xi2 = Xb[p * 3 + 2];
    const float vi0 = Vb[p * 3 + 0], vi1 = Vb[p * 3 + 1], vi2 = Vb[p * 3 + 2];

    const float base = bb + w[0] * xi0 + w[1] * xi1 + w[2] * xi2
                          + w[6] * vi0 + w[7] * vi1 + w[8] * vi2;

    __shared__ float nb[4][NNBR][8];
    if (lane < NNBR) {
        const int j = (int)nbr[(uint)gp * NNBR + lane];
        nb[wave][lane][0] = Xb[j * 3 + 0];
        nb[wave][lane][1] = Xb[j * 3 + 1];
        nb[wave][lane][2] = Xb[j * 3 + 2];
        nb[wave][lane][3] = Vb[j * 3 + 0];
        nb[wave][lane][4] = Vb[j * 3 + 1];
        nb[wave][lane][5] = Vb[j * 3 + 2];
    }
    __syncthreads();

    float acc = 0.0f;
#pragma unroll
    for (int n = 0; n < NNBR; ++n) {
        const float h = base + w[3]  * nb[wave][n][0] + w[4]  * nb[wave][n][1]
                             + w[5]  * nb[wave][n][2] + w[9]  * nb[wave][n][3]
                             + w[10] * nb[wave][n][4] + w[11] * nb[wave][n][5];
        acc += fmaxf(h, 0.0f);
    }

    out[(size_t)gp * 64 + lane] = acc * (1.0f / 16.0f);
}

extern "C" void kernel_launch(void* const* d_in, const int* in_sizes, int n_in,
                              void* d_out, int out_size, void* d_ws, size_t ws_size,
                              hipStream_t stream) {
    const float* x0 = (const float*)d_in[0];   // (4, 12288)
    const float* v0 = (const float*)d_in[1];   // (4, 12288)
    const float* W  = (const float*)d_in[2];   // (12, 64)
    const float* bb = (const float*)d_in[3];   // (64,)
    float* out = (float*)d_out;

    ushort* nbr = (ushort*)d_ws;               // 16384 * 16 * 2B = 512 KB

    // 1) fused exact 16-NN: 1024 blocks (4 batches x 256 chunks of 16 points),
    //    512 threads (16 pts x 32 segs).
    knn_kernel<<<1024, 512, 0, stream>>>(x0, nbr);

    // 2) MLP + mean (+ folded v0 copy): 4 points/block, 4096 blocks.
    mlp_kernel<<<4096, 256, 0, stream>>>(x0, v0, W, bb, nbr, out);
}

// Round 7
// 72.391 us; speedup vs baseline: 1.4360x; 1.4360x over previous
//
#include <hip/hip_runtime.h>
#include <hip/hip_bf16.h>
#include <stdint.h>

#define NPTS 4096
#define NNBR 16      // neighbors kept (reference keeps 17 incl. self, drops self)
#define PPB  16      // points per block
#define NSEG 32      // candidate segments (one per t>>4 group)
#define SEGLEN 128   // candidates per segment
#define SEGPAD 132   // 132 % 32 == 4: the 4 segs in a wave land on bank-quads 0/4/8/12
#define HSTR 65      // heads/plist stride in floats
#define LSTR 97      // list stride (uints)
#define CAP  96      // accepted-candidate capacity (rank(tau) ~ 20-40)
#define TAUM 1.0e-3f // proxy-vs-pinned margin (bound ~4e-5; 25x safety)
#define BIGD 3.4e38f

// ---------------------------------------------------------------------------
// PINNED distance (numpy-order, no contraction) — used ONLY in the final
// threshold/marking phases so the selected neighbor set is bitwise-stable:
//   d2 = (sqp + sqq) - (dot + dot)
// ---------------------------------------------------------------------------
__device__ __forceinline__ float sqnorm(float x, float y, float z) {
    return __fadd_rn(__fadd_rn(__fmul_rn(x, x), __fmul_rn(y, y)), __fmul_rn(z, z));
}
__device__ __forceinline__ float d2w(float px, float py, float pz, float sqp,
                                     float cx, float cy, float cz, float sqq) {
    const float dot = __fadd_rn(__fadd_rn(__fmul_rn(px, cx), __fmul_rn(py, cy)),
                                __fmul_rn(pz, cz));
    return __fsub_rn(__fadd_rn(sqp, sqq), __fadd_rn(dot, dot));
}
// CHEAP monotone proxy for the scans: e = sqq - 2*dot  (= d2 - sqp up to ~ulps).
// 4 VALU: mul, fma, fma, fma. Per-point constant sqp drops out of ordering;
// TAUM margin in scan2 absorbs all proxy-vs-pinned rounding differences.
__device__ __forceinline__ float eproxy(float px, float py, float pz,
                                        float cx, float cy, float cz, float sqq) {
    const float dot = __builtin_fmaf(px, cx, __builtin_fmaf(py, cy, __fmul_rn(pz, cz)));
    return __builtin_fmaf(dot, -2.0f, sqq);
}

// generic K-deep min/max ladder over a register array (static unroll only)
#define LADK(AD, K, S)                                            \
    _Pragma("unroll")                                             \
    for (int k_ = 0; k_ < (K); ++k_) {                            \
        const float lo_ = fminf((S), AD[k_]);                     \
        (S) = fmaxf((S), AD[k_]);                                 \
        AD[k_] = lo_;                                             \
    }

// ---------------------------------------------------------------------------
// Fused exact 16-NN. Block = 512 thr = 16 points x 32 segments, grid = 1024.
//  scan1 : per-seg top-2 of proxy-e via min/max tree (12 VALU per 4 cands).
//  tau   : heads[pt][64]; 2 thr/pt LAD17 one 32-value half; tau = min of the
//          two 17th-smallest values  >=  true e_(17)  [subset order-stat].
//  scan2 : branchless {e <= tau+TAUM} bitmask; sparse extraction appends
//          candidate index to per-point LDS list (atomic, CAP=96).
//  final : PINNED d2 — 2-slice LAD16 partials -> exact 16th-smallest ->
//          marking pass emits the 16 indices (identical sets to round 5/6).
// ---------------------------------------------------------------------------
__global__ __launch_bounds__(512, 4) void knn_kernel(const float* __restrict__ x0,
                                                     ushort* __restrict__ nbr) {
    __shared__ float sx[NSEG * SEGPAD], sy[NSEG * SEGPAD],
                     sz[NSEG * SEGPAD], sw[NSEG * SEGPAD];   // 4 x 16,896 B
    __shared__ float mbuf[PPB * HSTR];                       // heads; later plist
    __shared__ uint  list[PPB * LSTR];                       // accepted indices
    __shared__ float ttau[PPB][2];
    __shared__ float t16[PPB];
    __shared__ int   cnt[PPB], cnt2[PPB];

    const int b     = blockIdx.x >> 8;       // 256 chunks per batch
    const int chunk = blockIdx.x & 255;
    const float* Xb = x0 + b * (NPTS * 3);
    const int t = threadIdx.x;

    for (int i = t; i < NPTS; i += 512) {
        const int a = (i >> 7) * SEGPAD + (i & 127);
        const float x = Xb[3 * i + 0];
        const float y = Xb[3 * i + 1];
        const float z = Xb[3 * i + 2];
        sx[a] = x; sy[a] = y; sz[a] = z; sw[a] = sqnorm(x, y, z);
    }
    if (t < PPB) { cnt[t] = 0; cnt2[t] = 0; }
    __syncthreads();

    const int pt = t & 15, seg = t >> 4;     // seg 0..31
    const int p  = chunk * PPB + pt;         // batch-local point id
    const int pa = (p >> 7) * SEGPAD + (p & 127);
    const float px = sx[pa], py = sy[pa], pz = sz[pa], sqp = sw[pa];
    const int sb = seg * SEGPAD;

    // ---- scan1: per-seg top-2 of proxy-e (self included: e_self ~ min) ----
    float a0 = BIGD, a1 = BIGD;              // a0 <= a1 invariant
    for (int j = 0; j < 32; ++j) {
        const int o = sb + 4 * j;
        const float4 cx4 = *(const float4*)&sx[o];
        const float4 cy4 = *(const float4*)&sy[o];
        const float4 cz4 = *(const float4*)&sz[o];
        const float4 cw4 = *(const float4*)&sw[o];
        const float s0 = eproxy(px, py, pz, cx4.x, cy4.x, cz4.x, cw4.x);
        const float s1 = eproxy(px, py, pz, cx4.y, cy4.y, cz4.y, cw4.y);
        const float s2 = eproxy(px, py, pz, cx4.z, cy4.z, cz4.z, cw4.z);
        const float s3 = eproxy(px, py, pz, cx4.w, cy4.w, cz4.w, cw4.w);
        // two smallest of the quad (tree, depth ~3)
        const float m01 = fminf(s0, s1), M01 = fmaxf(s0, s1);
        const float m23 = fminf(s2, s3), M23 = fmaxf(s2, s3);
        const float mm  = fminf(m01, m23);
        const float ss  = fminf(fmaxf(m01, m23), fminf(M01, M23));
        // merge sorted pairs (a0,a1) x (mm,ss) -> new two smallest
        const float n0 = fminf(a0, mm);
        a1 = fminf(fmaxf(a0, mm), fminf(a1, ss));
        a0 = n0;
    }
    mbuf[pt * HSTR + seg * 2 + 0] = a0;
    mbuf[pt * HSTR + seg * 2 + 1] = a1;
    __syncthreads();

    // ---- tau: 2 thr/pt, LAD17 over one 32-value half (rotated reads) ----
    if (t < 32) {
        const int pm = t >> 1, half = t & 1;
        float ad[17];
#pragma unroll
        for (int k = 0; k < 17; ++k) ad[k] = BIGD;
        const int base = pm * HSTR + half * 32;
        for (int e = 0; e < 32; ++e) {
            float s = mbuf[base + ((e + 2 * t) & 31)];
            LADK(ad, 17, s)
        }
        ttau[pm][half] = ad[16];             // this half's 17th-smallest
    }
    __syncthreads();

    // ---- scan2: branchless accept-bitmask per 32-cand word + extraction ----
    const float tv = fminf(ttau[pt][0], ttau[pt][1]) + TAUM;
    for (int w = 0; w < 4; ++w) {
        uint m = 0;
#pragma unroll
        for (int jj = 0; jj < 8; ++jj) {
            const int o = sb + w * 32 + 4 * jj;
            const float4 cx4 = *(const float4*)&sx[o];
            const float4 cy4 = *(const float4*)&sy[o];
            const float4 cz4 = *(const float4*)&sz[o];
            const float4 cw4 = *(const float4*)&sw[o];
            const float s0 = eproxy(px, py, pz, cx4.x, cy4.x, cz4.x, cw4.x);
            const float s1 = eproxy(px, py, pz, cx4.y, cy4.y, cz4.y, cw4.y);
            const float s2 = eproxy(px, py, pz, cx4.z, cy4.z, cz4.z, cw4.z);
            const float s3 = eproxy(px, py, pz, cx4.w, cy4.w, cz4.w, cw4.w);
            m |= (s0 <= tv) ? (1u << (4 * jj + 0)) : 0u;
            m |= (s1 <= tv) ? (1u << (4 * jj + 1)) : 0u;
            m |= (s2 <= tv) ? (1u << (4 * jj + 2)) : 0u;
            m |= (s3 <= tv) ? (1u << (4 * jj + 3)) : 0u;
        }
        while (m) {                          // ~1 set bit/thread total
            const int bpos = __ffs(m) - 1;
            m &= m - 1;
            const int q = seg * SEGLEN + w * 32 + bpos;   // batch-local cand id
            if (q != p) {
                const int o = atomicAdd(&cnt[pt], 1);
                if (o < CAP) list[pt * LSTR + o] = (uint)q;
            }
        }
    }
    __syncthreads();

    // ---- final 3a: 2 thr/pt, PINNED-d2 LAD16 over stride-2 slice ----
    if (t < 32) {
        const int p2 = t >> 1, sl = t & 1;
        const int n  = min(cnt[p2], CAP);
        const int pg  = chunk * PPB + p2;
        const int pa2 = (pg >> 7) * SEGPAD + (pg & 127);
        const float ax = sx[pa2], ay = sy[pa2], az = sz[pa2], sqa = sw[pa2];
        float ad[16];
#pragma unroll
        for (int k = 0; k < 16; ++k) ad[k] = BIGD;
        for (int e = sl; e < n; e += 2) {
            const int q  = (int)list[p2 * LSTR + e];
            const int qa = (q >> 7) * SEGPAD + (q & 127);
            float s = d2w(ax, ay, az, sqa, sx[qa], sy[qa], sz[qa], sw[qa]);
            LADK(ad, 16, s)
        }
#pragma unroll
        for (int k = 0; k < 16; ++k) mbuf[p2 * HSTR + sl * 16 + k] = ad[k];
    }
    __syncthreads();

    // ---- final 3b: 1 thr/pt, exact 16th-smallest pinned d2 among accepted ----
    if (t < PPB) {
        float ad[16];
#pragma unroll
        for (int k = 0; k < 16; ++k) ad[k] = BIGD;
        for (int e = 0; e < 32; ++e) {
            float s = mbuf[t * HSTR + ((e + t) & 31)];
            LADK(ad, 16, s)
        }
        t16[t] = ad[15];
    }
    __syncthreads();

    // ---- final 3c: marking pass emits the 16 indices with pinned d2 <= th ----
    if (t < 64) {
        const int p2 = t >> 2, sl = t & 3;
        const int n  = min(cnt[p2], CAP);
        const int pg  = chunk * PPB + p2;
        const int pa2 = (pg >> 7) * SEGPAD + (pg & 127);
        const float ax = sx[pa2], ay = sy[pa2], az = sz[pa2], sqa = sw[pa2];
        const float th = t16[p2];
        const uint base = (uint)(b * NPTS + pg) * (uint)NNBR;
        for (int e = sl; e < n; e += 4) {
            const int q  = (int)list[p2 * LSTR + e];
            const int qa = (q >> 7) * SEGPAD + (q & 127);
            const float s = d2w(ax, ay, az, sqa, sx[qa], sy[qa], sz[qa], sw[qa]);
            if (s <= th) {
                const int o = atomicAdd(&cnt2[p2], 1);
                if (o < NNBR) nbr[base + o] = (ushort)q;
            }
        }
    }
}

// ---------------------------------------------------------------------------
// MLP + neighbor mean (one wave per point, lane = output channel) with the
// v0 passthrough copy folded in (first 48 blocks copy one float4/thread).
// ---------------------------------------------------------------------------
__global__ __launch_bounds__(256) void mlp_kernel(const float* __restrict__ x0,
                                                  const float* __restrict__ v0,
                                                  const float* __restrict__ W,
                                                  const float* __restrict__ bias,
                                                  const ushort* __restrict__ nbr,
                                                  float* __restrict__ out) {
    const int t   = threadIdx.x;
    const int gid = blockIdx.x * 256 + t;
    if (gid < (4 * NPTS * 3) / 4) {                 // 12288 float4 copies
        ((float4*)(out + 4 * NPTS * 64))[gid] = ((const float4*)v0)[gid];
    }

    const int wave = t >> 6;
    const int lane = t & 63;
    const int gp   = blockIdx.x * 4 + wave;         // global point id 0..16383
    const int b    = gp >> 12;
    const int p    = gp & (NPTS - 1);

    const float* Xb = x0 + b * (NPTS * 3);
    const float* Vb = v0 + b * (NPTS * 3);

    float w[12];
#pragma unroll
    for (int k = 0; k < 12; ++k) w[k] = W[k * 64 + lane];
    const float bb = bias[lane];

    const float xi0 = Xb[p * 3 + 0], xi1 = Xb[p * 3 + 1], xi2 = Xb[p * 3 + 2];
    const float vi0 = Vb[p * 3 + 0], vi1 = Vb[p * 3 + 1], vi2 = Vb[p * 3 + 2];

    const float base = bb + w[0] * xi0 + w[1] * xi1 + w[2] * xi2
                          + w[6] * vi0 + w[7] * vi1 + w[8] * vi2;

    __shared__ float nb[4][NNBR][8];
    if (lane < NNBR) {
        const int j = (int)nbr[(uint)gp * NNBR + lane];
        nb[wave][lane][0] = Xb[j * 3 + 0];
        nb[wave][lane][1] = Xb[j * 3 + 1];
        nb[wave][lane][2] = Xb[j * 3 + 2];
        nb[wave][lane][3] = Vb[j * 3 + 0];
        nb[wave][lane][4] = Vb[j * 3 + 1];
        nb[wave][lane][5] = Vb[j * 3 + 2];
    }
    __syncthreads();

    float acc = 0.0f;
#pragma unroll
    for (int n = 0; n < NNBR; ++n) {
        const float h = base + w[3]  * nb[wave][n][0] + w[4]  * nb[wave][n][1]
                             + w[5]  * nb[wave][n][2] + w[9]  * nb[wave][n][3]
                             + w[10] * nb[wave][n][4] + w[11] * nb[wave][n][5];
        acc += fmaxf(h, 0.0f);
    }

    out[(size_t)gp * 64 + lane] = acc * (1.0f / 16.0f);
}

extern "C" void kernel_launch(void* const* d_in, const int* in_sizes, int n_in,
                              void* d_out, int out_size, void* d_ws, size_t ws_size,
                              hipStream_t stream) {
    const float* x0 = (const float*)d_in[0];   // (4, 12288)
    const float* v0 = (const float*)d_in[1];   // (4, 12288)
    const float* W  = (const float*)d_in[2];   // (12, 64)
    const float* bb = (const float*)d_in[3];   // (64,)
    float* out = (float*)d_out;

    ushort* nbr = (ushort*)d_ws;               // 16384 * 16 * 2B = 512 KB

    // 1) fused exact 16-NN: 1024 blocks (4 batches x 256 chunks of 16 points),
    //    512 threads (16 pts x 32 segs).
    knn_kernel<<<1024, 512, 0, stream>>>(x0, nbr);

    // 2) MLP + mean (+ folded v0 copy): 4 points/block, 4096 blocks.
    mlp_kernel<<<4096, 256, 0, stream>>>(x0, v0, W, bb, nbr, out);
}